// Round 1
// baseline (534.539 us; speedup 1.0000x reference)
//
#include <hip/hip_runtime.h>

// Problem constants (decoderHead: B=4, S=4096, E=512, DK=64), all fp32 I/O.
constexpr int BB = 4;
constexpr int SS = 4096;
constexpr int EE = 512;

typedef __attribute__((ext_vector_type(8))) short bf16x8;
typedef __attribute__((ext_vector_type(4))) float f32x4;

union Frag {
  uint4 u4;
  unsigned int u[4];
  bf16x8 v;
};

__device__ __forceinline__ unsigned short f2bf(float f) {
  union { float f; unsigned int u; } v; v.f = f;
  unsigned int r = v.u + 0x7FFFu + ((v.u >> 16) & 1u);   // RNE
  return (unsigned short)(r >> 16);
}
__device__ __forceinline__ float bf2f(unsigned short h) {
  union { unsigned int u; float f; } v; v.u = ((unsigned int)h) << 16;
  return v.f;
}

// ---------------------------------------------------------------------------
// Kernel 1: Q/K/V projections + pad-mask.
//   Q = (x@Wq)*mask -> bf16 [B][S][64]
//   K = (ctx@Wk)*mask -> bf16 [B][S][64]
//   V = (ctx@Wv)*mask -> bf16 TRANSPOSED Vt[B][64][S]  (for PV B-operand)
//   mask[B*S] f32
// Block: 256 thr (4 waves), 32 rows/block; W staged in LDS in E-chunks of 64.
// x/ctx rows read with wave-uniform float4 loads (broadcast).
// ---------------------------------------------------------------------------
__global__ __launch_bounds__(256, 2) void proj_kernel(
    const float* __restrict__ x, const float* __restrict__ ctx,
    const float* __restrict__ Wq, const float* __restrict__ Wk,
    const float* __restrict__ Wv,
    unsigned short* __restrict__ Qb, unsigned short* __restrict__ Kb,
    unsigned short* __restrict__ Vt, float* __restrict__ maskp)
{
  __shared__ float wsm[3 * 64 * 64];          // [mat][e(64)][d(64)]
  __shared__ unsigned int orbuf[32][8];

  const int t = threadIdx.x;
  const int l = t & 63;
  const int b  = blockIdx.x >> 7;
  const int s0 = (blockIdx.x & 127) << 5;     // 32 rows per block

  // --- pre-pass: zero-row detection on x (bit-OR; <<1 drops sign of -0.0) ---
  {
    const int row = t >> 3, part = t & 7;     // 32 rows x 8 parts x 64 floats
    const uint4* xr = (const uint4*)(x + ((size_t)(b * SS + s0 + row)) * EE + part * 64);
    unsigned int o = 0;
#pragma unroll
    for (int j = 0; j < 16; ++j) { uint4 u = xr[j]; o |= u.x | u.y | u.z | u.w; }
    orbuf[row][part] = o;
  }

  const int wi = __builtin_amdgcn_readfirstlane((int)(threadIdx.x >> 6));
  const float* xw = x   + ((size_t)(b * SS + s0 + wi * 8)) * EE;
  const float* cw = ctx + ((size_t)(b * SS + s0 + wi * 8)) * EE;

  float accq[8] = {0,0,0,0,0,0,0,0};
  float acck[8] = {0,0,0,0,0,0,0,0};
  float accv[8] = {0,0,0,0,0,0,0,0};

  const float4* wq4 = (const float4*)Wq;
  const float4* wk4 = (const float4*)Wk;
  const float4* wv4 = (const float4*)Wv;

  for (int c = 0; c < 8; ++c) {               // E-chunks of 64
    __syncthreads();
#pragma unroll
    for (int j = 0; j < 4; ++j) {
      int idx4 = t + j * 256;                 // 1024 float4 per matrix chunk
      ((float4*)wsm)[idx4]        = wq4[c * 1024 + idx4];
      ((float4*)wsm)[1024 + idx4] = wk4[c * 1024 + idx4];
      ((float4*)wsm)[2048 + idx4] = wv4[c * 1024 + idx4];
    }
    __syncthreads();
#pragma unroll 4
    for (int e4 = 0; e4 < 16; ++e4) {
      float wqv[4], wkv[4], wvv[4];
#pragma unroll
      for (int ee = 0; ee < 4; ++ee) {
        int eo = (e4 * 4 + ee) * 64 + l;
        wqv[ee] = wsm[eo];
        wkv[ee] = wsm[4096 + eo];
        wvv[ee] = wsm[8192 + eo];
      }
#pragma unroll
      for (int i = 0; i < 8; ++i) {
        float4 xv = ((const float4*)(xw + (size_t)i * EE))[c * 16 + e4];
        float4 cv = ((const float4*)(cw + (size_t)i * EE))[c * 16 + e4];
        accq[i] = fmaf(xv.w, wqv[3], fmaf(xv.z, wqv[2], fmaf(xv.y, wqv[1], fmaf(xv.x, wqv[0], accq[i]))));
        acck[i] = fmaf(cv.w, wkv[3], fmaf(cv.z, wkv[2], fmaf(cv.y, wkv[1], fmaf(cv.x, wkv[0], acck[i]))));
        accv[i] = fmaf(cv.w, wvv[3], fmaf(cv.z, wvv[2], fmaf(cv.y, wvv[1], fmaf(cv.x, wvv[0], accv[i]))));
      }
    }
  }
  __syncthreads();

  float mv[8];
#pragma unroll
  for (int i = 0; i < 8; ++i) {
    unsigned int o = 0;
#pragma unroll
    for (int p = 0; p < 8; ++p) o |= orbuf[wi * 8 + i][p];
    mv[i] = ((o << 1) != 0u) ? 1.0f : 0.0f;
  }
#pragma unroll
  for (int i = 0; i < 8; ++i) {
    size_t s = (size_t)(b * SS + s0 + wi * 8 + i);
    Qb[s * 64 + l] = f2bf(accq[i] * mv[i]);
    Kb[s * 64 + l] = f2bf(acck[i] * mv[i]);
    if (l == 0) maskp[s] = mv[i];
  }
  unsigned int vpack[4];
#pragma unroll
  for (int j = 0; j < 4; ++j) {
    unsigned int lo = f2bf(accv[2 * j]     * mv[2 * j]);
    unsigned int hi = f2bf(accv[2 * j + 1] * mv[2 * j + 1]);
    vpack[j] = lo | (hi << 16);
  }
  uint4 vv = make_uint4(vpack[0], vpack[1], vpack[2], vpack[3]);
  *(uint4*)(Vt + ((size_t)(b * 64 + l)) * SS + (s0 + wi * 8)) = vv;
}

// ---------------------------------------------------------------------------
// Kernel 2: lengths[b] = #{k : dot(Q[b,0,:], K[b,k,:]) != 0}
// ---------------------------------------------------------------------------
__global__ __launch_bounds__(256) void len_kernel(
    const unsigned short* __restrict__ Qb,
    const unsigned short* __restrict__ Kb,
    unsigned int* __restrict__ lenp)
{
  __shared__ float q0row[64];
  const int t = threadIdx.x;
  const int b = blockIdx.y;
  if (t < 64) q0row[t] = bf2f(Qb[(size_t)b * SS * 64 + t]);
  __syncthreads();
  const int k = blockIdx.x * 256 + t;
  const unsigned short* kr = Kb + ((size_t)(b * SS + k)) * 64;
  float acc = 0.f;
#pragma unroll
  for (int d = 0; d < 64; ++d) acc = fmaf(q0row[d], bf2f(kr[d]), acc);
  unsigned long long bal = __ballot(acc != 0.0f);
  if ((t & 63) == 0) atomicAdd(&lenp[b], (unsigned int)__popcll(bal));
}

// ---------------------------------------------------------------------------
// Kernel 3: flash attention. 128 thr (2 waves), 32 queries/block, KV tiles 64.
// LDS: K tile [64key][64d] bf16 XOR-swizzled; Vt tile [64d][64key] swizzled;
// P via padded LDS [16][66] bf16 per wave (C-layout -> A-fragment relayout).
// ---------------------------------------------------------------------------
__global__ __launch_bounds__(128) void attn_kernel(
    const unsigned short* __restrict__ Qb,
    const unsigned short* __restrict__ Kb,
    const unsigned short* __restrict__ Vt,
    const float* __restrict__ maskp,
    const unsigned int* __restrict__ lenp,
    float* __restrict__ out)
{
  __shared__ __align__(16) unsigned int ks[2048];            // 8KB
  __shared__ __align__(16) unsigned int vs[2048];            // 8KB
  __shared__ __align__(16) unsigned short ps[2][16][66];     // 4.1KB

  const int t  = threadIdx.x;
  const int l  = t & 63;
  const int wi = t >> 6;
  const int g  = l >> 4;
  const int li = l & 15;
  const int b  = blockIdx.y;
  const int q0 = blockIdx.x * 32;

  const unsigned int len = lenp[b];

  Frag qf0, qf1;
  {
    const uint4* qg = (const uint4*)(Qb + ((size_t)(b * SS + q0 + wi * 16 + li)) * 64);
    qf0.u4 = qg[g];
    qf1.u4 = qg[4 + g];
  }

  f32x4 O[4] = {};
  float m_r[4] = {-1e30f, -1e30f, -1e30f, -1e30f};
  float l_r[4] = {0.f, 0.f, 0.f, 0.f};

  for (int tile = 0; tile < SS / 64; ++tile) {
    const int key0 = tile * 64;
    if ((unsigned)key0 >= len) break;          // uniform across grid
    __syncthreads();                            // prev-iter LDS reads done
    {
#pragma unroll
      for (int it = 0; it < 4; ++it) {
        int flat = t + it * 128;
        int row = flat >> 3, ch = flat & 7;
        uint4 kval = ((const uint4*)Kb)[((size_t)(b * SS + key0)) * 8 + flat];
        *(uint4*)&ks[row * 32 + ((ch ^ (row & 7)) << 2)] = kval;
        uint4 vval = ((const uint4*)Vt)[((size_t)(b * 64 + row)) * 512 + (key0 >> 3) + ch];
        *(uint4*)&vs[row * 32 + ((ch ^ (row & 7)) << 2)] = vval;
      }
    }
    __syncthreads();

    // ---- S = Q K^T  (A=Q frag, B=K rows; k-axis = d, same mapping both) ----
    f32x4 acc[4] = {};
#pragma unroll
    for (int f = 0; f < 2; ++f) {
      const Frag& qf = f ? qf1 : qf0;
      int cb = f * 4 + g;
#pragma unroll
      for (int a = 0; a < 4; ++a) {
        int krow = a * 16 + li;
        Frag kf;
        kf.u4 = *(const uint4*)&ks[krow * 32 + ((cb ^ (krow & 7)) << 2)];
        acc[a] = __builtin_amdgcn_mfma_f32_16x16x32_bf16(qf.v, kf.v, acc[a], 0, 0, 0);
      }
    }

    // ---- online softmax (logits in log2 units: *0.125*log2e) ----
    const float SC = 0.18033688011112042f;
    bool bad[4];
#pragma unroll
    for (int a = 0; a < 4; ++a) bad[a] = ((unsigned)(key0 + a * 16 + li) >= len);
    float p[4][4];
#pragma unroll
    for (int r = 0; r < 4; ++r)
#pragma unroll
      for (int a = 0; a < 4; ++a)
        p[a][r] = bad[a] ? -1e30f : acc[a][r] * SC;

#pragma unroll
    for (int r = 0; r < 4; ++r) {
      float tm = fmaxf(fmaxf(p[0][r], p[1][r]), fmaxf(p[2][r], p[3][r]));
      tm = fmaxf(tm, __shfl_xor(tm, 1));
      tm = fmaxf(tm, __shfl_xor(tm, 2));
      tm = fmaxf(tm, __shfl_xor(tm, 4));
      tm = fmaxf(tm, __shfl_xor(tm, 8));
      float nm = fmaxf(m_r[r], tm);
      float al = exp2f(m_r[r] - nm);
      m_r[r] = nm;
      float rs = 0.f;
#pragma unroll
      for (int a = 0; a < 4; ++a) { float pv = exp2f(p[a][r] - nm); p[a][r] = pv; rs += pv; }
      rs += __shfl_xor(rs, 1);
      rs += __shfl_xor(rs, 2);
      rs += __shfl_xor(rs, 4);
      rs += __shfl_xor(rs, 8);
      l_r[r] = l_r[r] * al + rs;
#pragma unroll
      for (int tt = 0; tt < 4; ++tt) O[tt][r] *= al;
    }

    // ---- P (C-layout) -> LDS -> A-fragment ----
#pragma unroll
    for (int a = 0; a < 4; ++a)
#pragma unroll
      for (int r = 0; r < 4; ++r)
        ps[wi][g * 4 + r][a * 16 + li] = f2bf(p[a][r]);
    __syncthreads();

    const unsigned int* pu = (const unsigned int*)&ps[0][0][0];
#pragma unroll
    for (int f = 0; f < 2; ++f) {
      Frag pf;
      int pb = wi * 528 + li * 33 + f * 16 + g * 4;
      pf.u[0] = pu[pb + 0]; pf.u[1] = pu[pb + 1];
      pf.u[2] = pu[pb + 2]; pf.u[3] = pu[pb + 3];
#pragma unroll
      for (int tt = 0; tt < 4; ++tt) {
        int vrow = tt * 16 + li;
        Frag vf;
        vf.u4 = *(const uint4*)&vs[vrow * 32 + (((f * 4 + g) ^ (vrow & 7)) << 2)];
        O[tt] = __builtin_amdgcn_mfma_f32_16x16x32_bf16(pf.v, vf.v, O[tt], 0, 0, 0);
      }
    }
  }

  // ---- epilogue: out = O * mask / l ----
#pragma unroll
  for (int r = 0; r < 4; ++r) {
    const int q = q0 + wi * 16 + g * 4 + r;
    const float sc = maskp[b * SS + q] / l_r[r];
#pragma unroll
    for (int tt = 0; tt < 4; ++tt)
      out[((size_t)(b * SS + q)) * 64 + tt * 16 + li] = O[tt][r] * sc;
  }
}

// ---------------------------------------------------------------------------
extern "C" void kernel_launch(void* const* d_in, const int* in_sizes, int n_in,
                              void* d_out, int out_size, void* d_ws, size_t ws_size,
                              hipStream_t stream) {
  const float* x   = (const float*)d_in[0];
  const float* ctx = (const float*)d_in[1];
  const float* Wq  = (const float*)d_in[2];
  const float* Wk  = (const float*)d_in[3];
  const float* Wv  = (const float*)d_in[4];
  float* out = (float*)d_out;

  char* ws = (char*)d_ws;
  unsigned short* Qb = (unsigned short*)(ws);                    // 2MB
  unsigned short* Kb = (unsigned short*)(ws + 2097152);          // 2MB
  unsigned short* Vt = (unsigned short*)(ws + 4194304);          // 2MB, [B][64][S]
  float* maskp       = (float*)(ws + 6291456);                   // 64KB
  unsigned int* lenp = (unsigned int*)(ws + 6291456 + 65536);    // 16B

  hipMemsetAsync(lenp, 0, 16, stream);
  proj_kernel<<<dim3(512), dim3(256), 0, stream>>>(x, ctx, Wq, Wk, Wv, Qb, Kb, Vt, maskp);
  len_kernel<<<dim3(16, 4), dim3(256), 0, stream>>>(Qb, Kb, lenp);
  attn_kernel<<<dim3(128, 4), dim3(128), 0, stream>>>(Qb, Kb, Vt, maskp, lenp, out);
}

// Round 2
// 211.777 us; speedup vs baseline: 2.5241x; 2.5241x over previous
//
#include <hip/hip_runtime.h>

// decoderHead: B=4, S=4096, E=512, DK=64, fp32 I/O.
constexpr int BB = 4;
constexpr int SS = 4096;
constexpr int EE = 512;
constexpr int BS = BB * SS;

typedef __attribute__((ext_vector_type(8))) short bf16x8;
typedef __attribute__((ext_vector_type(4))) float f32x4;
typedef unsigned long long ull;

union Frag {
  uint4 u4;
  unsigned int u[4];
  bf16x8 v;
};

__device__ __forceinline__ unsigned short f2bf(float f) {
  union { float f; unsigned int u; } v; v.f = f;
  unsigned int r = v.u + 0x7FFFu + ((v.u >> 16) & 1u);   // RNE
  return (unsigned short)(r >> 16);
}
__device__ __forceinline__ float bf2f(unsigned short h) {
  union { unsigned int u; float f; } v; v.u = ((unsigned int)h) << 16;
  return v.f;
}
__device__ __forceinline__ unsigned int packbf(float a, float b) {
  return (unsigned int)f2bf(a) | ((unsigned int)f2bf(b) << 16);
}

// ---------------------------------------------------------------------------
// mask_kernel: maskp[row] = any(x[row,:] != +-0)  (one wave per row)
// ---------------------------------------------------------------------------
__global__ __launch_bounds__(256) void mask_kernel(const float* __restrict__ x,
                                                   float* __restrict__ maskp) {
  const int row = blockIdx.x * 4 + (threadIdx.x >> 6);
  const int l = threadIdx.x & 63;
  const uint4* xr = (const uint4*)(x + (size_t)row * EE) + l;
  uint4 a = xr[0], b = xr[64];
  unsigned int o = (a.x | a.y | a.z | a.w | b.x | b.y | b.z | b.w) << 1;
  bool nz = __any(o != 0u);
  if (l == 0) maskp[row] = nz ? 1.0f : 0.0f;
}

// ---------------------------------------------------------------------------
// proj_kernel: fp32 tiled GEMM. z=0: Q=x@Wq; z=1: K=ctx@Wk; z=2: V=ctx@Wv.
// Block 256 thr computes 64 rows x 64 cols; thread tile 4x4; KC=32 dbuf.
// Outputs masked bf16; V written transposed Vt[b][d][s].
// ---------------------------------------------------------------------------
__global__ __launch_bounds__(256) void proj_kernel(
    const float* __restrict__ x, const float* __restrict__ ctx,
    const float* __restrict__ Wq, const float* __restrict__ Wk,
    const float* __restrict__ Wv, const float* __restrict__ maskp,
    unsigned short* __restrict__ Qb, unsigned short* __restrict__ Kb,
    unsigned short* __restrict__ Vt)
{
  __shared__ __align__(16) float At[2][32][68];   // [k][row], +4 pad
  __shared__ __align__(16) float Wl[2][32][64];   // [k][col]

  const int t = threadIdx.x;
  const int z = blockIdx.y;
  const int r0g = blockIdx.x * 64;

  const float* A = (z == 0) ? x : ctx;
  const float* W = (z == 0) ? Wq : (z == 1) ? Wk : Wv;

  const int arow = t >> 3;          // 0..31
  const int ak   = (t & 7) << 2;    // 0..28
  const int wk   = t >> 4;          // 0..15
  const int wc   = (t & 15) << 2;   // 0..60

  float4 ar0, ar1, wv0, wv1;
  auto stage_load = [&](int kc) {
    ar0 = *(const float4*)(A + (size_t)(r0g + arow) * EE + kc + ak);
    ar1 = *(const float4*)(A + (size_t)(r0g + arow + 32) * EE + kc + ak);
    wv0 = *(const float4*)(W + (size_t)(kc + wk) * 64 + wc);
    wv1 = *(const float4*)(W + (size_t)(kc + wk + 16) * 64 + wc);
  };
  auto stage_write = [&](int buf) {
    At[buf][ak + 0][arow] = ar0.x; At[buf][ak + 1][arow] = ar0.y;
    At[buf][ak + 2][arow] = ar0.z; At[buf][ak + 3][arow] = ar0.w;
    At[buf][ak + 0][arow + 32] = ar1.x; At[buf][ak + 1][arow + 32] = ar1.y;
    At[buf][ak + 2][arow + 32] = ar1.z; At[buf][ak + 3][arow + 32] = ar1.w;
    *(float4*)&Wl[buf][wk][wc] = wv0;
    *(float4*)&Wl[buf][wk + 16][wc] = wv1;
  };

  const int r0 = (t & 15) << 2;     // local row 0..60
  const int c0 = (t >> 4) << 2;     // col 0..60
  float acc[4][4] = {};

  stage_load(0);
  stage_write(0);
  int cur = 0;
  for (int c = 0; c < 16; ++c) {
    if (c < 15) stage_load((c + 1) * 32);
    __syncthreads();
#pragma unroll 8
    for (int kk = 0; kk < 32; ++kk) {
      float4 av = *(const float4*)&At[cur][kk][r0];
      float4 wv = *(const float4*)&Wl[cur][kk][c0];
      acc[0][0] = fmaf(av.x, wv.x, acc[0][0]); acc[0][1] = fmaf(av.x, wv.y, acc[0][1]);
      acc[0][2] = fmaf(av.x, wv.z, acc[0][2]); acc[0][3] = fmaf(av.x, wv.w, acc[0][3]);
      acc[1][0] = fmaf(av.y, wv.x, acc[1][0]); acc[1][1] = fmaf(av.y, wv.y, acc[1][1]);
      acc[1][2] = fmaf(av.y, wv.z, acc[1][2]); acc[1][3] = fmaf(av.y, wv.w, acc[1][3]);
      acc[2][0] = fmaf(av.z, wv.x, acc[2][0]); acc[2][1] = fmaf(av.z, wv.y, acc[2][1]);
      acc[2][2] = fmaf(av.z, wv.z, acc[2][2]); acc[2][3] = fmaf(av.z, wv.w, acc[2][3]);
      acc[3][0] = fmaf(av.w, wv.x, acc[3][0]); acc[3][1] = fmaf(av.w, wv.y, acc[3][1]);
      acc[3][2] = fmaf(av.w, wv.z, acc[3][2]); acc[3][3] = fmaf(av.w, wv.w, acc[3][3]);
    }
    __syncthreads();
    if (c < 15) stage_write(cur ^ 1);
    cur ^= 1;
  }

  float mk[4];
#pragma unroll
  for (int i = 0; i < 4; ++i) mk[i] = maskp[r0g + r0 + i];
  if (z == 2) {
    const int b = r0g >> 12;
    const int sl = (r0g & 4095) + r0;
#pragma unroll
    for (int j = 0; j < 4; ++j) {
      ull v = (ull)f2bf(acc[0][j] * mk[0])
            | ((ull)f2bf(acc[1][j] * mk[1]) << 16)
            | ((ull)f2bf(acc[2][j] * mk[2]) << 32)
            | ((ull)f2bf(acc[3][j] * mk[3]) << 48);
      *(ull*)(Vt + ((size_t)(b * 64 + c0 + j)) * SS + sl) = v;
    }
  } else {
    unsigned short* O = (z == 0) ? Qb : Kb;
#pragma unroll
    for (int i = 0; i < 4; ++i) {
      ull v = (ull)f2bf(acc[i][0] * mk[i])
            | ((ull)f2bf(acc[i][1] * mk[i]) << 16)
            | ((ull)f2bf(acc[i][2] * mk[i]) << 32)
            | ((ull)f2bf(acc[i][3] * mk[i]) << 48);
      *(ull*)(O + (size_t)(r0g + r0 + i) * 64 + c0) = v;
    }
  }
}

// ---------------------------------------------------------------------------
// len_kernel: lengths[b] = #{k : dot(Q[b,0,:], K[b,k,:]) != 0}
// ---------------------------------------------------------------------------
__global__ __launch_bounds__(256) void len_kernel(
    const unsigned short* __restrict__ Qb,
    const unsigned short* __restrict__ Kb,
    unsigned int* __restrict__ lenp)
{
  __shared__ float q0row[64];
  const int t = threadIdx.x;
  const int b = blockIdx.y;
  if (t < 64) q0row[t] = bf2f(Qb[(size_t)b * SS * 64 + t]);
  __syncthreads();
  const int k = blockIdx.x * 256 + t;
  const unsigned short* kr = Kb + ((size_t)(b * SS + k)) * 64;
  float acc = 0.f;
#pragma unroll
  for (int d = 0; d < 64; ++d) acc = fmaf(q0row[d], bf2f(kr[d]), acc);
  unsigned long long bal = __ballot(acc != 0.0f);
  if ((t & 63) == 0) atomicAdd(&lenp[b], (unsigned int)__popcll(bal));
}

// ---------------------------------------------------------------------------
// attn_kernel: flash attention, swapped-QK^T (lane owns one q-row of P).
// 256 thr (4 waves x 16q), KV tile 64, double-buffered staging, KV-split.
// Writes unnormalized partials Op + (m,l) per row; combine normalizes.
// ---------------------------------------------------------------------------
__global__ __launch_bounds__(256) void attn_kernel(
    const unsigned short* __restrict__ Qb,
    const unsigned short* __restrict__ Kb,
    const unsigned short* __restrict__ Vt,
    const unsigned int* __restrict__ lenp,
    float* __restrict__ Op, float* __restrict__ mlp, int nsplit)
{
  __shared__ __align__(16) unsigned int ks[2][2048];       // [64key][64d] bf16, XOR-swz
  __shared__ __align__(16) unsigned int vs[2][2048];       // [64d][64key] bf16, XOR-swz
  __shared__ __align__(16) unsigned int ps[4 * 16 * 36];   // per-wave P [16q][72bf16]

  const int t  = threadIdx.x;
  const int l  = t & 63;
  const int wi = t >> 6;
  const int g  = l >> 4;
  const int li = l & 15;
  const int b  = blockIdx.z;
  const int sp = blockIdx.y;
  const int q0 = blockIdx.x * 64;

  const unsigned int len = lenp[b];
  const int kvChunk = SS / nsplit;
  const int kvS = sp * kvChunk;
  const int kvE = min((int)len, kvS + kvChunk);
  const int NT  = max(0, (kvE - kvS + 63) >> 6);

  Frag qf0, qf1;
  {
    const uint4* qg = (const uint4*)(Qb + ((size_t)(b * SS + q0 + wi * 16 + li)) * 64);
    qf0.u4 = qg[g]; qf1.u4 = qg[4 + g];
  }

  f32x4 O[4] = {};
  float m_r = -1e30f, l_r = 0.f;

  const int srow = t >> 3;   // 0..31 (second pass: +32)
  const int sch  = t & 7;
  uint4 kr0, kr1, vr0, vr1;
  auto stage_load = [&](int key0) {
    const unsigned short* Kbase = Kb + ((size_t)(b * SS + key0)) * 64;
    kr0 = *(const uint4*)(Kbase + (size_t)srow * 64 + sch * 8);
    kr1 = *(const uint4*)(Kbase + (size_t)(srow + 32) * 64 + sch * 8);
    const unsigned short* Vbase = Vt + (size_t)b * 64 * SS + key0;
    vr0 = *(const uint4*)(Vbase + (size_t)srow * SS + sch * 8);
    vr1 = *(const uint4*)(Vbase + (size_t)(srow + 32) * SS + sch * 8);
  };
  auto stage_write = [&](int buf) {
    *(uint4*)&ks[buf][srow * 32 + ((sch ^ (srow & 7)) << 2)] = kr0;
    *(uint4*)&ks[buf][(srow + 32) * 32 + ((sch ^ (srow & 7)) << 2)] = kr1;
    *(uint4*)&vs[buf][srow * 32 + ((sch ^ (srow & 7)) << 2)] = vr0;
    *(uint4*)&vs[buf][(srow + 32) * 32 + ((sch ^ (srow & 7)) << 2)] = vr1;
  };

  int cur = 0;
  if (NT > 0) { stage_load(kvS); stage_write(0); }
  for (int tix = 0; tix < NT; ++tix) {
    const int key0 = kvS + tix * 64;
    if (tix + 1 < NT) stage_load(key0 + 64);   // issue early; lands at stage_write
    __syncthreads();

    // ---- S^T = K Q^T : D[key=(g*4+r)+16a][q=li] ----
    f32x4 acc[4] = {};
#pragma unroll
    for (int f = 0; f < 2; ++f) {
      const bf16x8 qv = f ? qf1.v : qf0.v;
      const int oc = f * 4 + g;
#pragma unroll
      for (int a = 0; a < 4; ++a) {
        const int krow = a * 16 + li;
        Frag kf; kf.u4 = *(const uint4*)&ks[cur][krow * 32 + ((oc ^ (krow & 7)) << 2)];
        acc[a] = __builtin_amdgcn_mfma_f32_16x16x32_bf16(kf.v, qv, acc[a], 0, 0, 0);
      }
    }

    // ---- online softmax, lane-local q=li, keys k = a*16 + g*4 + r ----
    const float SC = 0.18033688011112042f;   // log2(e)/sqrt(64)
    const int lim = kvE - key0;
    float pv[4][4];
    float tm = -1e30f;
#pragma unroll
    for (int a = 0; a < 4; ++a)
#pragma unroll
      for (int r = 0; r < 4; ++r) {
        const int kk = a * 16 + (g << 2) + r;
        const float v = (kk < lim) ? acc[a][r] * SC : -1e30f;
        pv[a][r] = v; tm = fmaxf(tm, v);
      }
    tm = fmaxf(tm, __shfl_xor(tm, 16));
    tm = fmaxf(tm, __shfl_xor(tm, 32));
    if (__any(tm > m_r + 8.f)) {             // defer-max: rescale rarely
      const float nm = fmaxf(m_r, tm);
      const float al = exp2f(m_r - nm);
      m_r = nm; l_r *= al;
      float alq[4];
#pragma unroll
      for (int r = 0; r < 4; ++r) alq[r] = __shfl(al, (l & 48) | (g << 2) | r);
#pragma unroll
      for (int o4 = 0; o4 < 4; ++o4)
#pragma unroll
        for (int r = 0; r < 4; ++r) O[o4][r] *= alq[r];
    }
    float rs = 0.f;
#pragma unroll
    for (int a = 0; a < 4; ++a)
#pragma unroll
      for (int r = 0; r < 4; ++r) { const float e = exp2f(pv[a][r] - m_r); pv[a][r] = e; rs += e; }
    rs += __shfl_xor(rs, 16);
    rs += __shfl_xor(rs, 32);
    l_r += rs;

    // ---- P -> per-wave LDS (wave-synchronous, no barrier) ----
    unsigned int* prow = &ps[(wi * 16 + li) * 36];
#pragma unroll
    for (int a = 0; a < 4; ++a) {
      prow[a * 8 + g * 2 + 0] = packbf(pv[a][0], pv[a][1]);
      prow[a * 8 + g * 2 + 1] = packbf(pv[a][2], pv[a][3]);
    }
    // ---- O += P V ----
#pragma unroll
    for (int f = 0; f < 2; ++f) {
      Frag pf; pf.u4 = *(const uint4*)&prow[f * 16 + g * 4];
      const int oc = f * 4 + g;
#pragma unroll
      for (int o4 = 0; o4 < 4; ++o4) {
        const int vrow = o4 * 16 + li;
        Frag vf; vf.u4 = *(const uint4*)&vs[cur][vrow * 32 + ((oc ^ (vrow & 7)) << 2)];
        O[o4] = __builtin_amdgcn_mfma_f32_16x16x32_bf16(pf.v, vf.v, O[o4], 0, 0, 0);
      }
    }
    __syncthreads();
    if (tix + 1 < NT) stage_write(cur ^ 1);
    cur ^= 1;
  }

  // ---- partial epilogue (unnormalized) ----
  const int qrow = q0 + wi * 16;
  if (g == 0) {
    mlp[(size_t)sp * 2 * BS + b * SS + qrow + li] = m_r;
    mlp[(size_t)sp * 2 * BS + BS + b * SS + qrow + li] = l_r;
  }
  const size_t obase = (size_t)sp * BS * 64;
#pragma unroll
  for (int o4 = 0; o4 < 4; ++o4)
#pragma unroll
    for (int r = 0; r < 4; ++r)
      Op[obase + ((size_t)(b * SS + qrow + (g << 2) + r)) * 64 + o4 * 16 + li] = O[o4][r];
}

// ---------------------------------------------------------------------------
// combine_kernel: merge kv-split partials, normalize, apply query mask.
// ---------------------------------------------------------------------------
__global__ __launch_bounds__(256) void combine_kernel(
    const float* __restrict__ Op, const float* __restrict__ mlp,
    const float* __restrict__ maskp, float* __restrict__ out, int nsplit)
{
  const int e = blockIdx.x * 256 + threadIdx.x;
  const int row = e >> 6;
  const float m0 = mlp[row], l0 = mlp[BS + row];
  const float o0 = Op[e];
  float res;
  if (nsplit == 2) {
    const float m1 = mlp[2 * BS + row], l1 = mlp[3 * BS + row];
    const float o1 = Op[(size_t)BS * 64 + e];
    const float M = fmaxf(m0, m1);
    const float w0 = (l0 > 0.f) ? exp2f(m0 - M) : 0.f;
    const float w1 = (l1 > 0.f) ? exp2f(m1 - M) : 0.f;
    const float lt = w0 * l0 + w1 * l1;
    const float sc = (lt > 0.f) ? maskp[row] / lt : 0.f;
    res = (w0 * o0 + w1 * o1) * sc;
  } else {
    res = (l0 > 0.f) ? o0 * (maskp[row] / l0) : 0.f;
  }
  out[e] = res;
}

// ---------------------------------------------------------------------------
extern "C" void kernel_launch(void* const* d_in, const int* in_sizes, int n_in,
                              void* d_out, int out_size, void* d_ws, size_t ws_size,
                              hipStream_t stream) {
  const float* x   = (const float*)d_in[0];
  const float* ctx = (const float*)d_in[1];
  const float* Wq  = (const float*)d_in[2];
  const float* Wk  = (const float*)d_in[3];
  const float* Wv  = (const float*)d_in[4];
  float* out = (float*)d_out;

  char* ws = (char*)d_ws;
  unsigned short* Qb = (unsigned short*)(ws);                    // 2MB
  unsigned short* Kb = (unsigned short*)(ws + 2097152);          // 2MB
  unsigned short* Vt = (unsigned short*)(ws + 4194304);          // 2MB [B][64][S]
  float* maskp       = (float*)(ws + 6291456);                   // 64KB
  unsigned int* lenp = (unsigned int*)(ws + 6356992);            // 256B
  float* Op          = (float*)(ws + 6357248);                   // nsplit*4MB
  // mlp after Op (sized for nsplit=2 worst case placement computed below)

  const size_t need2 = 6357248ull + 8388608ull + 262144ull;      // ~14.3MB
  const int nsplit = (ws_size >= need2) ? 2 : 1;
  float* mlp = (float*)(ws + 6357248 + (size_t)nsplit * 4194304);

  hipMemsetAsync(lenp, 0, 16, stream);
  mask_kernel<<<dim3(BS / 4), 256, 0, stream>>>(x, maskp);
  proj_kernel<<<dim3(BS / 64, 3), 256, 0, stream>>>(x, ctx, Wq, Wk, Wv, maskp, Qb, Kb, Vt);
  len_kernel<<<dim3(16, 4), 256, 0, stream>>>(Qb, Kb, lenp);
  attn_kernel<<<dim3(SS / 64, nsplit, BB), 256, 0, stream>>>(Qb, Kb, Vt, lenp, Op, mlp, nsplit);
  combine_kernel<<<dim3(BS * 64 / 256), 256, 0, stream>>>(Op, mlp, maskp, out, nsplit);
}

// Round 3
// 170.022 us; speedup vs baseline: 3.1439x; 1.2456x over previous
//
#include <hip/hip_runtime.h>

// decoderHead: B=4, S=4096, E=512, DK=64, fp32 I/O.
constexpr int BB = 4;
constexpr int SS = 4096;
constexpr int EE = 512;
constexpr int BS = BB * SS;

typedef __attribute__((ext_vector_type(8))) short bf16x8;
typedef __attribute__((ext_vector_type(4))) float f32x4;
typedef unsigned long long ull;

union Frag {
  uint4 u4;
  unsigned int u[4];
  bf16x8 v;
};

__device__ __forceinline__ unsigned short f2bf(float f) {
  unsigned int u = __float_as_uint(f);
  unsigned int r = u + 0x7FFFu + ((u >> 16) & 1u);   // RNE
  return (unsigned short)(r >> 16);
}
__device__ __forceinline__ float bf2f(unsigned short h) {
  return __uint_as_float(((unsigned int)h) << 16);
}
__device__ __forceinline__ unsigned int cvtpk(float a, float b) {
  unsigned int r;
  asm("v_cvt_pk_bf16_f32 %0, %1, %2" : "=v"(r) : "v"(a), "v"(b));
  return r;  // lo = bf16(a), hi = bf16(b)
}
// global -> LDS direct (16B/lane). Dest must be wave-uniform base; src per-lane.
__device__ __forceinline__ void gl16(const unsigned short* g, unsigned int* l) {
  __builtin_amdgcn_global_load_lds(
      (const __attribute__((address_space(1))) unsigned int*)(size_t)g,
      (__attribute__((address_space(3))) unsigned int*)(unsigned int)(size_t)l,
      16, 0, 0);
}
#define WAITVM(n) asm volatile("s_waitcnt vmcnt(" #n ")" ::: "memory")

// split 8 fp32 -> hi bf16x8 (truncate) + lo bf16x8 (residual, truncate)
__device__ __forceinline__ void split8(const float* v, uint4& H, uint4& L) {
  unsigned int hu[4], lu[4];
#pragma unroll
  for (int i = 0; i < 4; ++i) {
    unsigned int u0 = __float_as_uint(v[2 * i]);
    unsigned int u1 = __float_as_uint(v[2 * i + 1]);
    unsigned int h0 = u0 & 0xFFFF0000u, h1 = u1 & 0xFFFF0000u;
    hu[i] = (u0 >> 16) | h1;
    unsigned int r0 = __float_as_uint(v[2 * i] - __uint_as_float(h0));
    unsigned int r1 = __float_as_uint(v[2 * i + 1] - __uint_as_float(h1));
    lu[i] = (r0 >> 16) | (r1 & 0xFFFF0000u);
  }
  H = make_uint4(hu[0], hu[1], hu[2], hu[3]);
  L = make_uint4(lu[0], lu[1], lu[2], lu[3]);
}

// ---------------------------------------------------------------------------
// mask_kernel: maskp[row] = any(x[row,:] != +-0)  (one wave per row)
// ---------------------------------------------------------------------------
__global__ __launch_bounds__(256) void mask_kernel(const float* __restrict__ x,
                                                   float* __restrict__ maskp) {
  const int row = blockIdx.x * 4 + (threadIdx.x >> 6);
  const int l = threadIdx.x & 63;
  const uint4* xr = (const uint4*)(x + (size_t)row * EE) + l;
  uint4 a = xr[0], b = xr[64];
  unsigned int o = (a.x | a.y | a.z | a.w | b.x | b.y | b.z | b.w) << 1;
  bool nz = __any(o != 0u);
  if (l == 0) maskp[row] = nz ? 1.0f : 0.0f;
}

// ---------------------------------------------------------------------------
// proj_kernel: MFMA projections via hi/lo bf16 decomposition (3-term).
// blockIdx.y==0: Q = (x@Wq)*SC (SC folded into W); blockIdx.y==1: K|V from ctx.
// Block 256 thr = 4 waves; 64 rows x {64 or 128} cols; K-chunks of 32, dbuf.
// LDS rows padded to 80B (stride 40 shorts): 2-way bank aliasing only.
// ---------------------------------------------------------------------------
__global__ __launch_bounds__(256, 2) void proj_kernel(
    const float* __restrict__ x, const float* __restrict__ ctx,
    const float* __restrict__ Wq, const float* __restrict__ Wk,
    const float* __restrict__ Wv, const float* __restrict__ maskp,
    unsigned short* __restrict__ Qb, unsigned short* __restrict__ Kb,
    unsigned short* __restrict__ Vt)
{
  __shared__ __align__(16) unsigned short Ah[2][64][40], Al[2][64][40];
  __shared__ __align__(16) unsigned short Wh[2][128][40], Wl[2][128][40];

  const int t = threadIdx.x;
  const int kvmode = blockIdx.y;
  const int r0g = blockIdx.x * 64;
  const int nlim = kvmode ? 8 : 4;

  const float* A = kvmode ? ctx : x;

  const int arow = t >> 2, akq = t & 3;    // A staging: 64 rows x 4x(8 floats)
  const int wn = t & 127, wkq = t >> 7;    // W staging: 128 n x 2x(16 floats)
  const int wn6 = wn & 63;
  const float* Wg = kvmode ? ((wn < 64) ? Wk : Wv) : Wq;
  const float wscale = kvmode ? 1.0f : 0.18033688011112042f;  // log2(e)/sqrt(64)
  const bool wact = kvmode || (wn < 64);

  float a8[8], w16[16];
  auto sload = [&](int kc) {
    const float* ap = A + (size_t)(r0g + arow) * EE + kc + akq * 8;
    *(float4*)&a8[0] = *(const float4*)ap;
    *(float4*)&a8[4] = *(const float4*)(ap + 4);
    if (wact) {
#pragma unroll
      for (int j = 0; j < 16; ++j)
        w16[j] = Wg[(size_t)(kc + wkq * 16 + j) * 64 + wn6] * wscale;
    }
  };
  auto swrite = [&](int buf) {
    uint4 H, L;
    split8(a8, H, L);
    *(uint4*)&Ah[buf][arow][akq * 8] = H;
    *(uint4*)&Al[buf][arow][akq * 8] = L;
    if (wact) {
      split8(w16, H, L);
      *(uint4*)&Wh[buf][wn][wkq * 16] = H;
      *(uint4*)&Wl[buf][wn][wkq * 16] = L;
      split8(w16 + 8, H, L);
      *(uint4*)&Wh[buf][wn][wkq * 16 + 8] = H;
      *(uint4*)&Wl[buf][wn][wkq * 16 + 8] = L;
    }
  };

  const int l = t & 63, wi = t >> 6, g = l >> 4, li = l & 15;
  f32x4 acc[8] = {};

  sload(0);
  swrite(0);
  int cur = 0;
  for (int c = 0; c < 16; ++c) {
    if (c < 15) sload((c + 1) * 32);
    __syncthreads();
    Frag ah, alo;
    ah.u4  = *(const uint4*)&Ah[cur][wi * 16 + li][g * 8];
    alo.u4 = *(const uint4*)&Al[cur][wi * 16 + li][g * 8];
#pragma unroll
    for (int nf = 0; nf < 8; ++nf) {
      if (nf < nlim) {
        Frag bh, bl;
        bh.u4 = *(const uint4*)&Wh[cur][nf * 16 + li][g * 8];
        bl.u4 = *(const uint4*)&Wl[cur][nf * 16 + li][g * 8];
        acc[nf] = __builtin_amdgcn_mfma_f32_16x16x32_bf16(ah.v, bh.v, acc[nf], 0, 0, 0);
        acc[nf] = __builtin_amdgcn_mfma_f32_16x16x32_bf16(alo.v, bh.v, acc[nf], 0, 0, 0);
        acc[nf] = __builtin_amdgcn_mfma_f32_16x16x32_bf16(ah.v, bl.v, acc[nf], 0, 0, 0);
      }
    }
    if (c < 15) swrite(cur ^ 1);   // other buffer: no barrier needed before next top-barrier
    cur ^= 1;
  }

  // epilogue: C row = g*4+r (m), col = li (n)
  float mk[4];
  const int browbase = r0g + wi * 16 + g * 4;
#pragma unroll
  for (int r = 0; r < 4; ++r) mk[r] = maskp[browbase + r];
  if (kvmode) {
#pragma unroll
    for (int nf = 0; nf < 4; ++nf)
#pragma unroll
      for (int r = 0; r < 4; ++r)
        Kb[(size_t)(browbase + r) * 64 + nf * 16 + li] = f2bf(acc[nf][r] * mk[r]);
    const int bidx = r0g >> 12;
    const int sbase = (r0g & 4095) + wi * 16 + g * 4;
#pragma unroll
    for (int nf = 4; nf < 8; ++nf) {
      unsigned int u0 = cvtpk(acc[nf][0] * mk[0], acc[nf][1] * mk[1]);
      unsigned int u1 = cvtpk(acc[nf][2] * mk[2], acc[nf][3] * mk[3]);
      ull v = (ull)u0 | ((ull)u1 << 32);
      *(ull*)(Vt + ((size_t)(bidx * 64 + (nf - 4) * 16 + li)) * SS + sbase) = v;
    }
  } else {
#pragma unroll
    for (int nf = 0; nf < 4; ++nf)
#pragma unroll
      for (int r = 0; r < 4; ++r)
        Qb[(size_t)(browbase + r) * 64 + nf * 16 + li] = f2bf(acc[nf][r] * mk[r]);
  }
}

// ---------------------------------------------------------------------------
// len_kernel: lengths[b] = #{k : dot(Q[b,0,:], K[b,k,:]) != 0}
// ---------------------------------------------------------------------------
__global__ __launch_bounds__(256) void len_kernel(
    const unsigned short* __restrict__ Qb,
    const unsigned short* __restrict__ Kb,
    unsigned int* __restrict__ lenp)
{
  __shared__ float q0row[64];
  const int t = threadIdx.x;
  const int b = blockIdx.y;
  if (t < 64) q0row[t] = bf2f(Qb[(size_t)b * SS * 64 + t]);
  __syncthreads();
  const int k = blockIdx.x * 256 + t;
  const uint4* kr = (const uint4*)(Kb + ((size_t)(b * SS + k)) * 64);
  float acc = 0.f;
#pragma unroll
  for (int j = 0; j < 8; ++j) {
    uint4 u = kr[j];
    unsigned int w[4] = {u.x, u.y, u.z, u.w};
#pragma unroll
    for (int q = 0; q < 4; ++q) {
      acc = fmaf(q0row[j * 8 + q * 2],     __uint_as_float(w[q] << 16), acc);
      acc = fmaf(q0row[j * 8 + q * 2 + 1], __uint_as_float(w[q] & 0xFFFF0000u), acc);
    }
  }
  unsigned long long bal = __ballot(acc != 0.0f);
  if ((t & 63) == 0) atomicAdd(&lenp[b], (unsigned int)__popcll(bal));
}

// ---------------------------------------------------------------------------
// attn tile body (shared by full / masked variants)
// ---------------------------------------------------------------------------
template <bool MASKED>
__device__ __forceinline__ void tile_body(
    const unsigned int* ksb, const unsigned int* vsb, unsigned int* prow,
    const Frag& qf0, const Frag& qf1, f32x4* O, float& m_r, float& l_r,
    int l, int g, int li, int lim)
{
  // S^T = K Q^T : lane owns q = li; keys kk = a*16 + g*4 + r (log2 units)
  f32x4 acc[4] = {};
#pragma unroll
  for (int f = 0; f < 2; ++f) {
    const bf16x8 qv = f ? qf1.v : qf0.v;
    const int oc = f * 4 + g;
#pragma unroll
    for (int a = 0; a < 4; ++a) {
      const int krow = a * 16 + li;
      Frag kf;
      kf.u4 = *(const uint4*)&ksb[krow * 32 + ((oc ^ (krow & 7)) << 2)];
      acc[a] = __builtin_amdgcn_mfma_f32_16x16x32_bf16(kf.v, qv, acc[a], 0, 0, 0);
    }
  }

  float pvv[4][4];
  float tm = -1e30f;
#pragma unroll
  for (int a = 0; a < 4; ++a)
#pragma unroll
    for (int r = 0; r < 4; ++r) {
      float v = acc[a][r];
      if (MASKED) v = (a * 16 + (g << 2) + r < lim) ? v : -1e30f;
      pvv[a][r] = v;
      tm = fmaxf(tm, v);
    }
  if (__any(tm > m_r + 8.f)) {          // defer-max: rarely taken
    float tq = fmaxf(tm, __shfl_xor(tm, 16));
    tq = fmaxf(tq, __shfl_xor(tq, 32));
    const float nm = fmaxf(m_r, tq);
    const float al = exp2f(m_r - nm);
    m_r = nm;
    l_r *= al;
    float alq[4];
#pragma unroll
    for (int r = 0; r < 4; ++r) alq[r] = __shfl(al, (l & 48) | (g << 2) | r);
#pragma unroll
    for (int o4 = 0; o4 < 4; ++o4)
#pragma unroll
      for (int r = 0; r < 4; ++r) O[o4][r] *= alq[r];
  }
  float rs = 0.f;
#pragma unroll
  for (int a = 0; a < 4; ++a)
#pragma unroll
    for (int r = 0; r < 4; ++r) {
      float e = exp2f(pvv[a][r] - m_r);
      pvv[a][r] = e;
      rs += e;
    }
  rs += __shfl_xor(rs, 16);
  rs += __shfl_xor(rs, 32);
  l_r += rs;

  // P -> per-wave LDS (wave-synchronous re-layout C->A), then O += P V
#pragma unroll
  for (int a = 0; a < 4; ++a) {
    prow[a * 8 + g * 2]     = cvtpk(pvv[a][0], pvv[a][1]);
    prow[a * 8 + g * 2 + 1] = cvtpk(pvv[a][2], pvv[a][3]);
  }
#pragma unroll
  for (int f = 0; f < 2; ++f) {
    Frag pf;
    pf.u4 = *(const uint4*)&prow[f * 16 + g * 4];
    const int oc = f * 4 + g;
#pragma unroll
    for (int o4 = 0; o4 < 4; ++o4) {
      const int vrow = o4 * 16 + li;
      Frag vf;
      vf.u4 = *(const uint4*)&vsb[vrow * 32 + ((oc ^ (vrow & 7)) << 2)];
      O[o4] = __builtin_amdgcn_mfma_f32_16x16x32_bf16(pf.v, vf.v, O[o4], 0, 0, 0);
    }
  }
}

// ---------------------------------------------------------------------------
// attn_kernel: flash attention, swapped-QK^T, NW waves x 16q, KV tiles 64.
// global_load_lds staging (pre-swizzled global source, linear LDS dest),
// raw s_barrier + counted vmcnt double-buffer. KV-split partials.
// ---------------------------------------------------------------------------
template <int NW>
__global__ __launch_bounds__(NW * 64, (NW == 8) ? 4 : 3) void attn_kernel(
    const unsigned short* __restrict__ Qb,
    const unsigned short* __restrict__ Kb,
    const unsigned short* __restrict__ Vt,
    const unsigned int* __restrict__ lenp,
    float* __restrict__ Op, float* __restrict__ mlp, int kvChunk)
{
  __shared__ __align__(16) unsigned int ks[2][2048];   // [64 key][64 d] bf16, swz
  __shared__ __align__(16) unsigned int vs[2][2048];   // [64 d][64 key] bf16, swz
  __shared__ __align__(16) unsigned int ps[NW * 16 * 36];

  constexpr int SPW = 16 / NW;   // 1KB staging segments per wave (ks+vs = 16)

  const int t  = threadIdx.x;
  const int l  = t & 63;
  const int wi = t >> 6;
  const int g  = l >> 4;
  const int li = l & 15;
  const int b  = blockIdx.z;
  const int sp = blockIdx.y;
  const int q0 = blockIdx.x * (NW * 16);

  const unsigned int len = lenp[b];
  const int kvS = sp * kvChunk;
  const int kvE = min((int)len, kvS + kvChunk);
  int rem = kvE - kvS; if (rem < 0) rem = 0;
  const int NF = rem >> 6;
  const int NT = NF + ((rem & 63) ? 1 : 0);

  Frag qf0, qf1;
  {
    const uint4* qg = (const uint4*)(Qb + ((size_t)(b * SS + q0 + wi * 16 + li)) * 64);
    qf0.u4 = qg[g];
    qf1.u4 = qg[4 + g];
  }

  f32x4 O[4] = {};
  float m_r = 0.f, l_r = 0.f;   // defer-max reference starts at 0

  const int srow8 = l >> 3;     // 0..7 within segment
  const int sch = l & 7;
  auto issue = [&](int key0, int bufsel) {
#pragma unroll
    for (int s2 = 0; s2 < SPW; ++s2) {
      const int seg = wi * SPW + s2;   // 0..15: first 8 = K, last 8 = V
      const int s8 = seg & 7;
      const int row = s8 * 8 + srow8;
      if (seg < 8) {
        gl16(Kb + ((size_t)(b * SS + key0 + row)) * 64 + ((sch ^ (row & 7)) << 3),
             &ks[bufsel][s8 * 256]);
      } else {
        gl16(Vt + ((size_t)(b * 64 + row)) * SS + key0 + ((sch ^ (row & 7)) << 3),
             &vs[bufsel][s8 * 256]);
      }
    }
  };

  unsigned int* prow = &ps[(wi * 16 + li) * 36];
  int cur = 0;
  if (NT > 0) issue(kvS, 0);
  for (int tix = 0; tix < NT; ++tix) {
    const int key0 = kvS + (tix << 6);
    const bool last = (tix + 1 == NT);
    if (!last) {
      issue(key0 + 64, cur ^ 1);
      if constexpr (NW == 8) { WAITVM(2); } else { WAITVM(4); }
    } else {
      WAITVM(0);
    }
    __builtin_amdgcn_s_barrier();
    __builtin_amdgcn_sched_barrier(0);
    const int lim = kvE - key0;
    if (tix < NF)
      tile_body<false>(&ks[cur][0], &vs[cur][0], prow, qf0, qf1, O, m_r, l_r, l, g, li, lim);
    else
      tile_body<true>(&ks[cur][0], &vs[cur][0], prow, qf0, qf1, O, m_r, l_r, l, g, li, lim);
    __builtin_amdgcn_s_barrier();   // readers done before next issue overwrites
    cur ^= 1;
  }

  // partial epilogue (unnormalized)
  const int qrow = q0 + wi * 16;
  if (g == 0) {
    mlp[(size_t)sp * 2 * BS + b * SS + qrow + li] = m_r;
    mlp[(size_t)sp * 2 * BS + BS + b * SS + qrow + li] = l_r;
  }
  const size_t obase = (size_t)sp * BS * 64;
#pragma unroll
  for (int o4 = 0; o4 < 4; ++o4)
#pragma unroll
    for (int r = 0; r < 4; ++r)
      Op[obase + ((size_t)(b * SS + qrow + (g << 2) + r)) * 64 + o4 * 16 + li] = O[o4][r];
}

// ---------------------------------------------------------------------------
// combine_kernel<NS>: merge kv-split partials, normalize, apply query mask.
// ---------------------------------------------------------------------------
template <int NS>
__global__ __launch_bounds__(256) void combine_kernel(
    const float* __restrict__ Op, const float* __restrict__ mlp,
    const float* __restrict__ maskp, float* __restrict__ out)
{
  const int i4 = blockIdx.x * 256 + threadIdx.x;
  const int e0 = i4 * 4;
  const int row = e0 >> 6;
  float ms[NS], lsv[NS];
#pragma unroll
  for (int s = 0; s < NS; ++s) {
    ms[s] = mlp[(size_t)s * 2 * BS + row];
    lsv[s] = mlp[(size_t)s * 2 * BS + BS + row];
  }
  float M = -1e30f;
#pragma unroll
  for (int s = 0; s < NS; ++s)
    if (lsv[s] > 0.f) M = fmaxf(M, ms[s]);
  float4 num = {0.f, 0.f, 0.f, 0.f};
  float den = 0.f;
#pragma unroll
  for (int s = 0; s < NS; ++s) {
    if (lsv[s] > 0.f) {
      const float w = exp2f(ms[s] - M);
      const float4 o = *(const float4*)(Op + (size_t)s * BS * 64 + e0);
      num.x += w * o.x; num.y += w * o.y; num.z += w * o.z; num.w += w * o.w;
      den += w * lsv[s];
    }
  }
  const float sc = (den > 0.f) ? maskp[row] / den : 0.f;
  float4 r = {num.x * sc, num.y * sc, num.z * sc, num.w * sc};
  *(float4*)(out + e0) = r;
}

// ---------------------------------------------------------------------------
extern "C" void kernel_launch(void* const* d_in, const int* in_sizes, int n_in,
                              void* d_out, int out_size, void* d_ws, size_t ws_size,
                              hipStream_t stream) {
  const float* x   = (const float*)d_in[0];
  const float* ctx = (const float*)d_in[1];
  const float* Wq  = (const float*)d_in[2];
  const float* Wk  = (const float*)d_in[3];
  const float* Wv  = (const float*)d_in[4];
  float* out = (float*)d_out;

  char* ws = (char*)d_ws;
  unsigned short* Qb = (unsigned short*)(ws);                    // 2MB (SC-folded)
  unsigned short* Kb = (unsigned short*)(ws + 2097152);          // 2MB
  unsigned short* Vt = (unsigned short*)(ws + 4194304);          // 2MB [B][64][S]
  float* maskp       = (float*)(ws + 6291456);                   // 64KB
  unsigned int* lenp = (unsigned int*)(ws + 6356992);            // 256B
  const size_t base = 6357248ull;

  const size_t need4 = base + 4ull * 4194304 + 4ull * 131072;
  const size_t need2 = base + 2ull * 4194304 + 2ull * 131072;
  int nsplit = (ws_size >= need4) ? 4 : (ws_size >= need2) ? 2 : 1;

  float* Op  = (float*)(ws + base);
  float* mlp = (float*)(ws + base + (size_t)nsplit * 4194304);

  hipMemsetAsync(lenp, 0, 16, stream);
  mask_kernel<<<dim3(BS / 4), 256, 0, stream>>>(x, maskp);
  proj_kernel<<<dim3(BS / 64, 2), 256, 0, stream>>>(x, ctx, Wq, Wk, Wv, maskp, Qb, Kb, Vt);
  len_kernel<<<dim3(16, 4), 256, 0, stream>>>(Qb, Kb, lenp);
  if (nsplit == 4) {
    attn_kernel<8><<<dim3(SS / 128, 4, BB), 512, 0, stream>>>(Qb, Kb, Vt, lenp, Op, mlp, 1024);
    combine_kernel<4><<<dim3(BS * 64 / 1024), 256, 0, stream>>>(Op, mlp, maskp, out);
  } else if (nsplit == 2) {
    attn_kernel<4><<<dim3(SS / 64, 2, BB), 256, 0, stream>>>(Qb, Kb, Vt, lenp, Op, mlp, 2048);
    combine_kernel<2><<<dim3(BS * 64 / 1024), 256, 0, stream>>>(Op, mlp, maskp, out);
  } else {
    attn_kernel<4><<<dim3(SS / 64, 1, BB), 256, 0, stream>>>(Qb, Kb, Vt, lenp, Op, mlp, 4096);
    combine_kernel<1><<<dim3(BS * 64 / 1024), 256, 0, stream>>>(Op, mlp, maskp, out);
  }
}